// Round 3
// baseline (84.914 us; speedup 1.0000x reference)
//
#include <hip/hip_runtime.h>

// SourcePE: out[n,b,e] = dropout( emb[n,b,e] + sin(box[b,n,e&3] * den[e>>2]) )
// dropout mask = JAX threefry2x32, key(42)=(0,42), partitionable path:
//   bits(i) = out0 ^ out1 of threefry((0,42), (0, i))
//   keep <=> bits < 7549747*512 = 3865470464   (bit-exact, verified R1/R2)

namespace {

typedef float f32x4 __attribute__((ext_vector_type(4)));

constexpr int      NBOX     = 1024;
constexpr unsigned TOTAL_G  = 1024u * 64u * 128u;  // 8388608 float4-groups
constexpr unsigned NBLK     = 8192;
constexpr unsigned NTHR     = 256;
constexpr unsigned STRIDE_G = NBLK * NTHR;         // 2097152
constexpr int      ITERS    = TOTAL_G / STRIDE_G;  // 4
// row-stride of a wave's 64 consecutive g is within one 128-group row half:
// row = g>>7 is wave-uniform (64 | 128), and stays so under g += STRIDE_G.

__device__ __forceinline__ unsigned rotl(unsigned x, int r) {
  return __builtin_amdgcn_alignbit(x, x, 32 - r);  // 1-op rotate
}

// threefry2x32, key=(0,42): ks0=0, ks1=42, ks2=0x1BD11BDA^42=0x1BD11BF0
__device__ __forceinline__ unsigned threefry_xor(unsigned ctr) {
  unsigned x0 = 0u;          // ctr_hi + ks0
  unsigned x1 = ctr + 42u;   // ctr_lo + ks1
#define R4(a,b,c,d)                       \
  x0 += x1; x1 = rotl(x1,(a)) ^ x0;       \
  x0 += x1; x1 = rotl(x1,(b)) ^ x0;       \
  x0 += x1; x1 = rotl(x1,(c)) ^ x0;       \
  x0 += x1; x1 = rotl(x1,(d)) ^ x0;
  R4(13,15,26,6)
  x0 += 42u;          x1 += 0x1BD11BF1u;  // ks1, ks2+1
  R4(17,29,16,24)
  x0 += 0x1BD11BF0u;  x1 += 2u;           // ks2, ks0+2
  R4(13,15,26,6)
  /* ks0 = 0 */       x1 += 45u;          // ks1+3
  R4(17,29,16,24)
  x0 += 42u;          x1 += 0x1BD11BF4u;  // ks1, ks2+4
  R4(13,15,26,6)
  x0 += 0x1BD11BF0u;  x1 += 5u;           // ks2, ks0+5
#undef R4
  return x0 ^ x1;
}

__global__ __launch_bounds__(256) void pe_add_dropout(
    const f32x4* __restrict__ emb,
    const int*   __restrict__ boxes,
    f32x4*       __restrict__ out) {
  const float K2 = 0.0064881408103268795f;  // log2(10000)/2048
  const float SC = 1.11111111111111111f;    // 1/0.9

  unsigned g = blockIdx.x * NTHR + threadIdx.x;   // < 2097152
  const unsigned j = g & 127u;
  const float den = exp2f(-(float)j * K2);        // j invariant per thread
  unsigned i0 = g << 2;                           // flat element index

  f32x4 e = emb[g];                               // pipeline: preloaded

#pragma unroll 2
  for (int it = 0; it < ITERS; ++it) {
    // --- prefetch next iteration's emb (clamped => wave-broadcast on last) ---
    const unsigned g_next = g + STRIDE_G;
    const unsigned g_pf   = g_next < TOTAL_G ? g_next : (TOTAL_G - 1u);
    const f32x4 e_next = emb[g_pf];

    // --- wave-uniform box -> scalar load path ---
    const unsigned row = __builtin_amdgcn_readfirstlane(g >> 7);  // n*64+b
    const int* bq = boxes + (((row & 63u) * NBOX + (row >> 6)) << 2);
    const int b0 = bq[0], b1 = bq[1], b2 = bq[2], b3 = bq[3];

    const float s0 = __sinf((float)b0 * den);
    const float s1 = __sinf((float)b1 * den);
    const float s2 = __sinf((float)b2 * den);
    const float s3 = __sinf((float)b3 * den);

    const unsigned m0 = threefry_xor(i0);
    const unsigned m1 = threefry_xor(i0 + 1u);
    const unsigned m2 = threefry_xor(i0 + 2u);
    const unsigned m3 = threefry_xor(i0 + 3u);

    f32x4 r;
    r.x = (m0 < 3865470464u) ? (e.x + s0) * SC : 0.0f;
    r.y = (m1 < 3865470464u) ? (e.y + s1) * SC : 0.0f;
    r.z = (m2 < 3865470464u) ? (e.z + s2) * SC : 0.0f;
    r.w = (m3 < 3865470464u) ? (e.w + s3) * SC : 0.0f;
    __builtin_nontemporal_store(r, &out[g]);

    e  = e_next;
    g  = g_next;
    i0 += STRIDE_G * 4u;
  }
}

}  // namespace

extern "C" void kernel_launch(void* const* d_in, const int* in_sizes, int n_in,
                              void* d_out, int out_size, void* d_ws, size_t ws_size,
                              hipStream_t stream) {
  const f32x4* emb   = (const f32x4*)d_in[0];  // (1024, 64, 512) f32
  const int*   boxes = (const int*)d_in[1];    // (64, 1024, 4) i32
  f32x4*       outp  = (f32x4*)d_out;          // (1024, 64, 512) f32
  hipLaunchKernelGGL(pe_add_dropout, dim3(NBLK), dim3(NTHR), 0, stream,
                     emb, boxes, outp);
}

// Round 4
// 71.581 us; speedup vs baseline: 1.1863x; 1.1863x over previous
//
#include <hip/hip_runtime.h>

// SourcePE: out[n,b,e] = dropout( emb[n,b,e] + sin(box[b,n,e&3] * den[e>>2]) )
// dropout mask = JAX threefry2x32, key(42)=(0,42), partitionable path:
//   bits(i) = out0 ^ out1 of threefry((0,42), (0, i))
//   keep <=> bits < 7549747*512 = 3865470464   (bit-exact, verified R1-R3)
//
// R4: R2 base (best: 78.5us) + 2-deep software pipeline (prologue/epilogue,
// no clamp) + pointer-increment addressing. R3's bundle (nt store, scalar box
// load, 8192-blk grid) regressed and is reverted.

namespace {

typedef float f32x4 __attribute__((ext_vector_type(4)));

constexpr int      NBOX     = 1024;
constexpr unsigned TOTAL_G  = 1024u * 64u * 128u;  // 8388608 float4-groups
constexpr unsigned NBLK     = 2048;                // = 8 blocks/CU, all co-resident
constexpr unsigned NTHR     = 256;
constexpr unsigned STRIDE_G = NBLK * NTHR;         // 524288 groups
constexpr int      ITERS    = TOTAL_G / STRIDE_G;  // 16
// per-thread: j = g&127 invariant, b invariant, n += 64 per iter
// => den hoisted, box ptr advances by 64 int4/iter.

__device__ __forceinline__ unsigned rotl(unsigned x, int r) {
  return __builtin_amdgcn_alignbit(x, x, 32 - r);  // 1-op rotate
}

// threefry2x32, key=(0,42): ks0=0, ks1=42, ks2=0x1BD11BDA^42=0x1BD11BF0
__device__ __forceinline__ unsigned threefry_xor(unsigned ctr) {
  unsigned x0 = 0u;          // ctr_hi + ks0
  unsigned x1 = ctr + 42u;   // ctr_lo + ks1
#define R4(a,b,c,d)                       \
  x0 += x1; x1 = rotl(x1,(a)) ^ x0;       \
  x0 += x1; x1 = rotl(x1,(b)) ^ x0;       \
  x0 += x1; x1 = rotl(x1,(c)) ^ x0;       \
  x0 += x1; x1 = rotl(x1,(d)) ^ x0;
  R4(13,15,26,6)
  x0 += 42u;          x1 += 0x1BD11BF1u;  // ks1, ks2+1
  R4(17,29,16,24)
  x0 += 0x1BD11BF0u;  x1 += 2u;           // ks2, ks0+2
  R4(13,15,26,6)
  /* ks0 = 0 */       x1 += 45u;          // ks1+3
  R4(17,29,16,24)
  x0 += 42u;          x1 += 0x1BD11BF4u;  // ks1, ks2+4
  R4(13,15,26,6)
  x0 += 0x1BD11BF0u;  x1 += 5u;           // ks2, ks0+5
#undef R4
  return x0 ^ x1;
}

__device__ __forceinline__ f32x4 body(const f32x4 e, const int4 bx,
                                      const float den, const unsigned i0) {
  const float SC = 1.11111111111111111f;  // 1/0.9
  const float s0 = __sinf((float)bx.x * den);
  const float s1 = __sinf((float)bx.y * den);
  const float s2 = __sinf((float)bx.z * den);
  const float s3 = __sinf((float)bx.w * den);

  const unsigned m0 = threefry_xor(i0);
  const unsigned m1 = threefry_xor(i0 + 1u);
  const unsigned m2 = threefry_xor(i0 + 2u);
  const unsigned m3 = threefry_xor(i0 + 3u);

  f32x4 r;
  r.x = (m0 < 3865470464u) ? (e.x + s0) * SC : 0.0f;
  r.y = (m1 < 3865470464u) ? (e.y + s1) * SC : 0.0f;
  r.z = (m2 < 3865470464u) ? (e.z + s2) * SC : 0.0f;
  r.w = (m3 < 3865470464u) ? (e.w + s3) * SC : 0.0f;
  return r;
}

__global__ __launch_bounds__(256) void pe_add_dropout(
    const f32x4* __restrict__ emb,
    const int4*  __restrict__ boxes,
    f32x4*       __restrict__ out) {
  const float K2 = 0.0064881408103268795f;  // log2(10000)/2048

  const unsigned g0   = blockIdx.x * NTHR + threadIdx.x;  // < 524288
  const unsigned j    = g0 & 127u;
  const unsigned row0 = g0 >> 7;            // n*64 + b, < 4096
  const unsigned b    = row0 & 63u;
  const unsigned n0   = row0 >> 6;          // < 64

  const float den = exp2f(-(float)j * K2); // hoisted: j invariant

  const f32x4* ep = emb + g0;
  const int4*  bp = boxes + (b * NBOX + n0);
  f32x4*       op = out + g0;
  unsigned     i0 = g0 << 2;               // flat element index

  // prologue: load iteration 0
  f32x4 e  = *ep;
  int4  bx = *bp;

#pragma unroll 3
  for (int it = 0; it < ITERS - 1; ++it) {
    // prefetch next iteration (no bounds check needed: it+1 <= ITERS-1)
    ep += STRIDE_G;
    bp += 64;                              // n += 64
    const f32x4 e_nx = *ep;
    const int4  b_nx = *bp;

    *op = body(e, bx, den, i0);

    op += STRIDE_G;
    i0 += STRIDE_G * 4u;
    e  = e_nx;
    bx = b_nx;
  }
  // epilogue: last iteration, no prefetch
  *op = body(e, bx, den, i0);
}

}  // namespace

extern "C" void kernel_launch(void* const* d_in, const int* in_sizes, int n_in,
                              void* d_out, int out_size, void* d_ws, size_t ws_size,
                              hipStream_t stream) {
  const f32x4* emb   = (const f32x4*)d_in[0];  // (1024, 64, 512) f32
  const int4*  boxes = (const int4*)d_in[1];   // (64, 1024, 4) i32
  f32x4*       outp  = (f32x4*)d_out;          // (1024, 64, 512) f32
  hipLaunchKernelGGL(pe_add_dropout, dim3(NBLK), dim3(NTHR), 0, stream,
                     emb, boxes, outp);
}